// Round 11
// baseline (525.170 us; speedup 1.0000x reference)
//
#include <hip/hip_runtime.h>
#include <hip/hip_bf16.h>
#include <math.h>

#define E   256
#define H   8
#define DH  32
#define LNUM 4
#define FF  1024
#define NN  64
#define MM  4096
#define TT  32
#define PP  2016   // 64*63/2
#define SPLIT 4
#define SEGLEN (MM/SPLIT)   // 1024
#define NT (SEGLEN/64)      // 16 key-tiles per segment

typedef __attribute__((ext_vector_type(8))) short short8;
typedef __attribute__((ext_vector_type(4))) short short4v;
typedef __attribute__((ext_vector_type(4))) float f32x4;

static __device__ __forceinline__ unsigned short f2bf(float x) {
    unsigned u = __float_as_uint(x);
    u = (u + 0x7fffu + ((u >> 16) & 1u)) >> 16;   // RNE
    return (unsigned short)u;
}
static __device__ __forceinline__ float bf2f(unsigned short u) {
    return __uint_as_float((unsigned)u << 16);
}

// ---------------- transpose-cast body (32x32 tile) ----------------
__device__ __forceinline__ void castT_body(float (*t)[33], const float* src,
        unsigned short* dst, int K, int N, int bx, int by, float scale, int tid) {
    int k0 = bx * 32, n0 = by * 32;
    int tx = tid & 31, ty = tid >> 5;
    #pragma unroll
    for (int i = 0; i < 4; ++i)
        t[ty + 8*i][tx] = src[(size_t)(k0 + ty + 8*i) * N + n0 + tx];
    __syncthreads();
    #pragma unroll
    for (int i = 0; i < 4; ++i)
        dst[(size_t)(n0 + ty + 8*i) * K + k0 + tx] = f2bf(t[tx][ty + 8*i] * scale);
}

// --- mega prep: rowcol+zerodiag+memcast+weight transposes+pairpre+textproj ---
__global__ __launch_bounds__(256)
void k_prep(const float* __restrict__ Wmem, const float* __restrict__ Wq,
            const float* __restrict__ Wk, const float* __restrict__ Wv,
            const float* __restrict__ Wo, const float* __restrict__ Wff1,
            const float* __restrict__ Wff2, const float* __restrict__ memory,
            unsigned short* __restrict__ Wmem_t, unsigned short* __restrict__ Wq_t,
            unsigned short* __restrict__ Wk_t, unsigned short* __restrict__ Wv_t,
            unsigned short* __restrict__ Wo_t, unsigned short* __restrict__ ff1_t,
            unsigned short* __restrict__ ff2_t, unsigned short* __restrict__ memb,
            int* __restrict__ rowp, int* __restrict__ colp,
            float* __restrict__ out, float QS,
            const float* __restrict__ h, const float* __restrict__ ref,
            const float* __restrict__ Wp, const float* __restrict__ bp,
            const float* __restrict__ Wr, float* __restrict__ PA,
            float* __restrict__ PB,
            const float* __restrict__ mrt, const float* __restrict__ Wt,
            const float* __restrict__ bt, float* __restrict__ txt) {
    __shared__ float t[32][33];
    __shared__ float fAs[16 * 68];
    __shared__ float fBs[16 * 68];
    int bid = blockIdx.x;
    int tid = threadIdx.x;
    if (bid < 8) {                     // rowcol
        int p = bid * 256 + tid;
        if (p < PP) {
            int off = p, r = 0;
            while (off >= (NN - 1 - r)) { off -= (NN - 1 - r); r++; }
            rowp[p] = r; colp[p] = r + 1 + off;
        }
        return;
    }
    bid -= 8;
    if (bid < 8) {                     // zerodiag
        int i = bid * 256 + tid;
        if (i < NN * TT) out[(size_t)((i >> 5) * 65) * TT + (i & 31)] = 0.f;
        return;
    }
    bid -= 8;
    if (bid < 1024) {                  // memory -> bf16
        int i = (bid * 256 + tid) * 4;
        float4 v = *(const float4*)(memory + i);
        short4v s;
        s[0] = (short)f2bf(v.x); s[1] = (short)f2bf(v.y);
        s[2] = (short)f2bf(v.z); s[3] = (short)f2bf(v.w);
        *(short4v*)(memb + i) = s;
        return;
    }
    bid -= 1024;
    if (bid < 17 * 64) {               // E x E transposes
        int z = bid >> 6, sub = bid & 63;
        const float* src; unsigned short* dst; float sc = 1.0f;
        if (z == 0)      { src = Wmem;               dst = Wmem_t; }
        else if (z < 5)  { src = Wq + (z-1)*E*E;     dst = Wq_t + (z-1)*E*E; sc = QS; }
        else if (z < 9)  { src = Wk + (z-5)*E*E;     dst = Wk_t + (z-5)*E*E; }
        else if (z < 13) { src = Wv + (z-9)*E*E;     dst = Wv_t + (z-9)*E*E; }
        else             { src = Wo + (z-13)*E*E;    dst = Wo_t + (z-13)*E*E; }
        castT_body(t, src, dst, E, E, sub >> 3, sub & 7, sc, tid);
        return;
    }
    bid -= 17 * 64;
    if (bid < 4 * 256) {               // ff1: K=E, N=FF
        int z = bid >> 8, sub = bid & 255;
        castT_body(t, Wff1 + (size_t)z*E*FF, ff1_t + (size_t)z*E*FF,
                   E, FF, sub >> 5, sub & 31, 1.f, tid);
        return;
    }
    bid -= 1024;
    if (bid < 4 * 256) {               // ff2: K=FF, N=E
        int z = bid >> 8, sub = bid & 255;
        castT_body(t, Wff2 + (size_t)z*FF*E, ff2_t + (size_t)z*FF*E,
                   FF, E, sub >> 3, sub & 7, 1.f, tid);
        return;
    }
    bid -= 1024;
    if (bid < 64) {                    // pairpre
        int r = bid, e = tid;
        float base = 0.5f * bp[e] + 0.5f * (ref[r*4+0] * Wr[e] + ref[r*4+1] * Wr[E + e]);
        float a = base, b = base;
        for (int k = 0; k < E; ++k) {
            float hv = h[r*E + k];
            a += hv * Wp[k*E + e];
            b += hv * Wp[(E + k)*E + e];
        }
        PA[r*E + e] = a;
        PB[r*E + e] = b;
        return;
    }
    // text projection: txt[TT,E] = mrt @ Wt + bt  (4 blocks, 64-col tiles)
    int n0 = (bid - 64) * 64;
    int tx = tid & 15, ty = tid >> 4;
    int am = tid >> 2, ak = (tid & 3) * 4;
    int bk = tid >> 4, bn = (tid & 15) * 4;
    bool avalid = am < TT;
    const float* Arow = mrt + (size_t)(avalid ? am : 0) * E;
    float acc[4][4] = {};
    for (int k0 = 0; k0 < E; k0 += 16) {
        __syncthreads();
        float4 av = make_float4(0.f, 0.f, 0.f, 0.f);
        if (avalid) av = *(const float4*)(Arow + k0 + ak);
        fAs[(ak+0)*68 + am] = av.x;
        fAs[(ak+1)*68 + am] = av.y;
        fAs[(ak+2)*68 + am] = av.z;
        fAs[(ak+3)*68 + am] = av.w;
        *(float4*)&fBs[bk*68 + bn] = *(const float4*)(Wt + (size_t)(k0 + bk) * E + n0 + bn);
        __syncthreads();
        #pragma unroll
        for (int kk = 0; kk < 16; ++kk) {
            float4 a4 = *(float4*)&fAs[kk*68 + ty*4];
            float4 b4 = *(float4*)&fBs[kk*68 + tx*4];
            float aa[4] = {a4.x, a4.y, a4.z, a4.w};
            float bb[4] = {b4.x, b4.y, b4.z, b4.w};
            #pragma unroll
            for (int i = 0; i < 4; ++i)
                #pragma unroll
                for (int j = 0; j < 4; ++j)
                    acc[i][j] += aa[i] * bb[j];
        }
    }
    float4 bi = *(const float4*)(bt + n0 + tx*4);
    float bb[4] = {bi.x, bi.y, bi.z, bi.w};
    #pragma unroll
    for (int i = 0; i < 4; ++i) {
        int m = ty*4 + i;
        if (m < TT) {
            float4 o;
            o.x = acc[i][0] + bb[0]; o.y = acc[i][1] + bb[1];
            o.z = acc[i][2] + bb[2]; o.w = acc[i][3] + bb[3];
            *(float4*)(txt + (size_t)m * E + n0 + tx*4) = o;
        }
    }
}

// ---------------- pair-build: q fp32 + qb bf16 (2016 blocks) ----------------
__global__ __launch_bounds__(256)
void k_qbuild(const int* __restrict__ row, const int* __restrict__ col,
              const float* __restrict__ PA, const float* __restrict__ PB,
              float* __restrict__ q, unsigned short* __restrict__ qb) {
    int p = blockIdx.x, e = threadIdx.x;
    float v = PA[row[p]*E + e] + PB[col[p]*E + e];
    q[p*E + e] = v;
    qb[p*E + e] = f2bf(v);
}

// ------------- 128x128-tile bf16 MFMA GEMM (for M=4096 GEMMs) --------------
__global__ __launch_bounds__(256)
void k_gemm_mfma(const unsigned short* __restrict__ A,
                 const unsigned short* __restrict__ Bt,
                 const float* __restrict__ bias,
                 float* __restrict__ C, unsigned short* __restrict__ Cb,
                 int M, int N, int K, int relu, float bscale) {
    __shared__ short As[128 * 64];
    __shared__ short Bs[128 * 64];
    int tid = threadIdx.x;
    int wave = tid >> 6, lane = tid & 63;
    int quad = lane >> 4, c = lane & 15;
    int m0 = blockIdx.x * 128, n0 = blockIdx.y * 128;
    const unsigned short* Bblk = Bt + (size_t)n0 * K;
    const float* biasblk = bias + n0;

    int gm[4], gk[4];
    const unsigned short* arow[4];
    #pragma unroll
    for (int j = 0; j < 4; ++j) {
        int g = tid + 256 * j;
        int T = g >> 6;
        gm[j] = (T & 7) * 16 + (g & 15);
        gk[j] = (T >> 3) * 32 + ((g >> 4) & 3) * 8;
        int r = m0 + gm[j];
        arow[j] = A + (size_t)(r < M ? r : M - 1) * K;
    }
    short8 pa[4], pb[4];
    #pragma unroll
    for (int j = 0; j < 4; ++j) {
        pa[j] = *(const short8*)(arow[j] + gk[j]);
        pb[j] = *(const short8*)(Bblk + (size_t)gm[j] * K + gk[j]);
    }
    f32x4 acc[4][4];
    #pragma unroll
    for (int i = 0; i < 4; ++i)
        #pragma unroll
        for (int j = 0; j < 4; ++j)
            acc[i][j] = (f32x4){0.f, 0.f, 0.f, 0.f};

    int wmt = (wave >> 1) * 4;
    int wnt = (wave & 1) * 4;
    int nk = K >> 6;
    for (int kt = 0; kt < nk; ++kt) {
        __syncthreads();
        #pragma unroll
        for (int j = 0; j < 4; ++j) {
            *(short8*)(As + (tid + 256 * j) * 8) = pa[j];
            *(short8*)(Bs + (tid + 256 * j) * 8) = pb[j];
        }
        __syncthreads();
        if (kt + 1 < nk) {
            int k0 = (kt + 1) * 64;
            #pragma unroll
            for (int j = 0; j < 4; ++j) {
                pa[j] = *(const short8*)(arow[j] + k0 + gk[j]);
                pb[j] = *(const short8*)(Bblk + (size_t)gm[j] * K + k0 + gk[j]);
            }
        }
        #pragma unroll
        for (int kc = 0; kc < 2; ++kc) {
            short8 af[4], bf[4];
            #pragma unroll
            for (int i = 0; i < 4; ++i)
                af[i] = *(short8*)(As + ((kc * 8 + wmt + i) * 64 + lane) * 8);
            #pragma unroll
            for (int j = 0; j < 4; ++j)
                bf[j] = *(short8*)(Bs + ((kc * 8 + wnt + j) * 64 + lane) * 8);
            #pragma unroll
            for (int i = 0; i < 4; ++i)
                #pragma unroll
                for (int j = 0; j < 4; ++j)
                    acc[i][j] = __builtin_amdgcn_mfma_f32_16x16x32_bf16(
                        af[i], bf[j], acc[i][j], 0, 0, 0);
        }
    }
    #pragma unroll
    for (int j = 0; j < 4; ++j) {
        float bv = biasblk[(wnt + j) * 16 + c] * bscale;
        int ng = n0 + (wnt + j) * 16 + c;
        #pragma unroll
        for (int i = 0; i < 4; ++i) {
            #pragma unroll
            for (int r = 0; r < 4; ++r) {
                int mg = m0 + (wmt + i) * 16 + quad * 4 + r;
                if (mg < M) {
                    float v = acc[i][j][r] + bv;
                    if (relu) v = fmaxf(v, 0.f);
                    size_t idx = (size_t)mg * N + ng;
                    if (C) C[idx] = v;
                    if (Cb) Cb[idx] = f2bf(v);
                }
            }
        }
    }
}

// --------- 64x128-tile bf16 MFMA GEMM (R9-proven) --------
__global__ __launch_bounds__(256)
void k_gemm64(const unsigned short* __restrict__ A,
              const unsigned short* __restrict__ Bt,
              const float* __restrict__ bias,
              float* __restrict__ C, unsigned short* __restrict__ Cb,
              int M, int N, int K, int relu, float bscale) {
    __shared__ short As[64 * 64];
    __shared__ short Bs[128 * 64];
    int tid = threadIdx.x;
    int wave = tid >> 6, lane = tid & 63;
    int quad = lane >> 4, c = lane & 15;
    int m0 = blockIdx.x * 64, n0 = blockIdx.y * 128;
    const unsigned short* Bblk = Bt + (size_t)n0 * K;
    const float* biasblk = bias + n0;

    int agk[2];
    const unsigned short* arow[2];
    #pragma unroll
    for (int j = 0; j < 2; ++j) {
        int g = tid + 256 * j;
        int T = g >> 6;
        int gm = (T & 3) * 16 + (g & 15);
        agk[j] = (T >> 2) * 32 + ((g >> 4) & 3) * 8;
        int r = m0 + gm;
        arow[j] = A + (size_t)(r < M ? r : M - 1) * K;
    }
    int bgk[4];
    const unsigned short* brow[4];
    #pragma unroll
    for (int j = 0; j < 4; ++j) {
        int g = tid + 256 * j;
        int T = g >> 6;
        int gn = (T & 7) * 16 + (g & 15);
        bgk[j] = (T >> 3) * 32 + ((g >> 4) & 3) * 8;
        brow[j] = Bblk + (size_t)gn * K;
    }
    short8 pa[2], pb[4];
    #pragma unroll
    for (int j = 0; j < 2; ++j) pa[j] = *(const short8*)(arow[j] + agk[j]);
    #pragma unroll
    for (int j = 0; j < 4; ++j) pb[j] = *(const short8*)(brow[j] + bgk[j]);

    f32x4 acc[2][4];
    #pragma unroll
    for (int i = 0; i < 2; ++i)
        #pragma unroll
        for (int j = 0; j < 4; ++j)
            acc[i][j] = (f32x4){0.f, 0.f, 0.f, 0.f};

    int wm = wave >> 1;
    int wn = wave & 1;
    int nk = K >> 6;
    for (int kt = 0; kt < nk; ++kt) {
        __syncthreads();
        #pragma unroll
        for (int j = 0; j < 2; ++j)
            *(short8*)(As + (tid + 256 * j) * 8) = pa[j];
        #pragma unroll
        for (int j = 0; j < 4; ++j)
            *(short8*)(Bs + (tid + 256 * j) * 8) = pb[j];
        __syncthreads();
        if (kt + 1 < nk) {
            int k0 = (kt + 1) * 64;
            #pragma unroll
            for (int j = 0; j < 2; ++j) pa[j] = *(const short8*)(arow[j] + k0 + agk[j]);
            #pragma unroll
            for (int j = 0; j < 4; ++j) pb[j] = *(const short8*)(brow[j] + k0 + bgk[j]);
        }
        #pragma unroll
        for (int kc = 0; kc < 2; ++kc) {
            short8 af[2], bf[4];
            #pragma unroll
            for (int i = 0; i < 2; ++i)
                af[i] = *(short8*)(As + ((kc * 4 + wm * 2 + i) * 64 + lane) * 8);
            #pragma unroll
            for (int j = 0; j < 4; ++j)
                bf[j] = *(short8*)(Bs + ((kc * 8 + wn * 4 + j) * 64 + lane) * 8);
            #pragma unroll
            for (int i = 0; i < 2; ++i)
                #pragma unroll
                for (int j = 0; j < 4; ++j)
                    acc[i][j] = __builtin_amdgcn_mfma_f32_16x16x32_bf16(
                        af[i], bf[j], acc[i][j], 0, 0, 0);
        }
    }
    #pragma unroll
    for (int j = 0; j < 4; ++j) {
        float bv = biasblk[(wn * 4 + j) * 16 + c] * bscale;
        int ng = n0 + (wn * 4 + j) * 16 + c;
        #pragma unroll
        for (int i = 0; i < 2; ++i) {
            #pragma unroll
            for (int r = 0; r < 4; ++r) {
                int mg = m0 + (wm * 2 + i) * 16 + quad * 4 + r;
                if (mg < M) {
                    float v = acc[i][j][r] + bv;
                    if (relu) v = fmaxf(v, 0.f);
                    size_t idx = (size_t)mg * N + ng;
                    if (C) C[idx] = v;
                    if (Cb) Cb[idx] = f2bf(v);
                }
            }
        }
    }
}

// ------- all-layer K/V projection ------------------------------------------
__global__ __launch_bounds__(256)
void k_kvproj(const unsigned short* __restrict__ A,
              const unsigned short* __restrict__ Wk_t,
              const unsigned short* __restrict__ Wv_t,
              const float* __restrict__ bk, const float* __restrict__ bv,
              unsigned short* __restrict__ Kout,
              unsigned short* __restrict__ Vtout) {
    __shared__ short As[128 * 64];
    __shared__ short Bs[128 * 64];
    int tid = threadIdx.x;
    int wave = tid >> 6, lane = tid & 63;
    int quad = lane >> 4, c = lane & 15;
    int m0 = blockIdx.x * 128, n0 = blockIdx.y * 128;
    int l = n0 >> 9, kv = (n0 >> 8) & 1, c0 = n0 & 255;
    const unsigned short* Bblk = (kv ? Wv_t : Wk_t) + (size_t)(l * E + c0) * E;
    const float* biasblk = (kv ? bv : bk) + l * E + c0;

    int gm[4], gk[4];
    const unsigned short* arow[4];
    #pragma unroll
    for (int j = 0; j < 4; ++j) {
        int g = tid + 256 * j;
        int T = g >> 6;
        gm[j] = (T & 7) * 16 + (g & 15);
        gk[j] = (T >> 3) * 32 + ((g >> 4) & 3) * 8;
        arow[j] = A + (size_t)(m0 + gm[j]) * E;
    }
    short8 pa[4], pb[4];
    #pragma unroll
    for (int j = 0; j < 4; ++j) {
        pa[j] = *(const short8*)(arow[j] + gk[j]);
        pb[j] = *(const short8*)(Bblk + (size_t)gm[j] * E + gk[j]);
    }
    f32x4 acc[4][4];
    #pragma unroll
    for (int i = 0; i < 4; ++i)
        #pragma unroll
        for (int j = 0; j < 4; ++j)
            acc[i][j] = (f32x4){0.f, 0.f, 0.f, 0.f};
    int wmt = (wave >> 1) * 4;
    int wnt = (wave & 1) * 4;
    for (int kt = 0; kt < 4; ++kt) {
        __syncthreads();
        #pragma unroll
        for (int j = 0; j < 4; ++j) {
            *(short8*)(As + (tid + 256 * j) * 8) = pa[j];
            *(short8*)(Bs + (tid + 256 * j) * 8) = pb[j];
        }
        __syncthreads();
        if (kt + 1 < 4) {
            int k0 = (kt + 1) * 64;
            #pragma unroll
            for (int j = 0; j < 4; ++j) {
                pa[j] = *(const short8*)(arow[j] + k0 + gk[j]);
                pb[j] = *(const short8*)(Bblk + (size_t)gm[j] * E + k0 + gk[j]);
            }
        }
        #pragma unroll
        for (int kc = 0; kc < 2; ++kc) {
            short8 af[4], bf[4];
            #pragma unroll
            for (int i = 0; i < 4; ++i)
                af[i] = *(short8*)(As + ((kc * 8 + wmt + i) * 64 + lane) * 8);
            #pragma unroll
            for (int j = 0; j < 4; ++j)
                bf[j] = *(short8*)(Bs + ((kc * 8 + wnt + j) * 64 + lane) * 8);
            #pragma unroll
            for (int i = 0; i < 4; ++i)
                #pragma unroll
                for (int j = 0; j < 4; ++j)
                    acc[i][j] = __builtin_amdgcn_mfma_f32_16x16x32_bf16(
                        af[i], bf[j], acc[i][j], 0, 0, 0);
        }
    }
    if (!kv) {
        unsigned short* Kp = Kout + (size_t)l * MM * E;
        #pragma unroll
        for (int j = 0; j < 4; ++j) {
            float bz = biasblk[(wnt + j) * 16 + c];
            int ng = c0 + (wnt + j) * 16 + c;
            #pragma unroll
            for (int i = 0; i < 4; ++i)
                #pragma unroll
                for (int r = 0; r < 4; ++r) {
                    int mg = m0 + (wmt + i) * 16 + quad * 4 + r;
                    Kp[(size_t)mg * E + ng] = f2bf(acc[i][j][r] + bz);
                }
        }
    } else {
        unsigned short* Vp = Vtout + (size_t)l * E * MM;
        #pragma unroll
        for (int j = 0; j < 4; ++j) {
            float bz = biasblk[(wnt + j) * 16 + c];
            int ng = c0 + (wnt + j) * 16 + c;
            #pragma unroll
            for (int i = 0; i < 4; ++i) {
                int mb = m0 + (wmt + i) * 16 + quad * 4;
                short4v s4;
                #pragma unroll
                for (int r = 0; r < 4; ++r) s4[r] = (short)f2bf(acc[i][j][r] + bz);
                *(short4v*)(Vp + (size_t)ng * MM + mb) = s4;
            }
        }
    }
}

// -------- flash cross-attention (R4/R9-proven): Opart bf16 ---------------
__global__ __launch_bounds__(256)
void k_attn2(const unsigned short* __restrict__ qph,
             const unsigned short* __restrict__ Kb,
             const unsigned short* __restrict__ Vt,
             unsigned short* __restrict__ Opb, float* __restrict__ Lsum) {
    __shared__ short KV[2 * 512 * 8];
    __shared__ short Plds[4 * 16 * 64];
    int tid = threadIdx.x;
    int wave = tid >> 6, lane = tid & 63;
    int quad = lane >> 4, c = lane & 15;
    int head = blockIdx.y, seg = blockIdx.z;
    int hc = head * DH;
    int prow0 = blockIdx.x * 64 + wave * 16;

    int pq = prow0 + c; if (pq > PP - 1) pq = PP - 1;
    short8 qf = *(const short8*)(qph + (size_t)pq * E + hc + quad * 8);

    int l = tid & 63;
    int tK = tid >> 6;
    const unsigned short* kgp = Kb + (size_t)(tK * 16 + (l & 15)) * E + hc + ((l >> 4) & 3) * 8;
    int sV = tid >> 7, ntV = (tid >> 6) & 1;
    const unsigned short* vgp = Vt + (size_t)(hc + ntV * 16 + (l & 15)) * MM
                                + sV * 32 + ((l >> 4) & 3) * 8;

    short* Pw = Plds + wave * 1024 + c * 64;
    int sw = (c & 7) << 1;

    f32x4 O0 = {0,0,0,0}, O1 = {0,0,0,0};
    float lsum = 0.f;

    int m0 = seg * SEGLEN;
    short8 pk = *(const short8*)(kgp + (size_t)m0 * E);
    short8 pv = *(const short8*)(vgp + m0);
    *(short8*)(KV + (size_t)tid * 8) = pk;
    *(short8*)(KV + ((size_t)256 + tid) * 8) = pv;

    int cur = 0;
    for (int kt = 0; kt < NT; ++kt) {
        __syncthreads();
        if (kt + 1 < NT) {
            int m1 = m0 + (kt + 1) * 64;
            pk = *(const short8*)(kgp + (size_t)m1 * E);
            pv = *(const short8*)(vgp + m1);
        }
        const short* Kc = KV + (size_t)cur * 512 * 8;
        f32x4 st[4];
        #pragma unroll
        for (int t = 0; t < 4; ++t) {
            short8 kf = *(const short8*)(Kc + (t * 64 + lane) * 8);
            f32x4 z = {0,0,0,0};
            st[t] = __builtin_amdgcn_mfma_f32_16x16x32_bf16(kf, qf, z, 0, 0, 0);
        }
        #pragma unroll
        for (int t = 0; t < 4; ++t) {
            float p0 = __builtin_amdgcn_exp2f(st[t][0]);
            float p1 = __builtin_amdgcn_exp2f(st[t][1]);
            float p2 = __builtin_amdgcn_exp2f(st[t][2]);
            float p3 = __builtin_amdgcn_exp2f(st[t][3]);
            lsum += (p0 + p1) + (p2 + p3);
            unsigned lo = (__float_as_uint(p1) & 0xffff0000u) | (__float_as_uint(p0) >> 16);
            unsigned hi = (__float_as_uint(p3) & 0xffff0000u) | (__float_as_uint(p2) >> 16);
            uint2 w; w.x = lo; w.y = hi;
            *(uint2*)(Pw + ((((t << 2) + quad) ^ sw) << 2)) = w;
        }
        const short* Vc = Kc + 256 * 8;
        #pragma unroll
        for (int s = 0; s < 2; ++s) {
            short8 pf  = *(const short8*)(Pw + (((s * 8 + 2 * quad) ^ sw) << 2));
            short8 vf0 = *(const short8*)(Vc + ((s * 2 + 0) * 64 + lane) * 8);
            short8 vf1 = *(const short8*)(Vc + ((s * 2 + 1) * 64 + lane) * 8);
            O0 = __builtin_amdgcn_mfma_f32_16x16x32_bf16(pf, vf0, O0, 0, 0, 0);
            O1 = __builtin_amdgcn_mfma_f32_16x16x32_bf16(pf, vf1, O1, 0, 0, 0);
        }
        if (kt + 1 < NT) {
            int nb = cur ^ 1;
            *(short8*)(KV + ((size_t)nb * 512 + tid) * 8) = pk;
            *(short8*)(KV + ((size_t)nb * 512 + 256 + tid) * 8) = pv;
        }
        cur ^= 1;
    }
    lsum += __shfl_xor(lsum, 16, 64);
    lsum += __shfl_xor(lsum, 32, 64);
    #pragma unroll
    for (int r = 0; r < 4; ++r) {
        int pg = prow0 + quad * 4 + r;
        if (pg < PP) {
            Opb[((size_t)seg * PP + pg) * E + hc + c]      = f2bf(O0[r]);
            Opb[((size_t)seg * PP + pg) * E + hc + 16 + c] = f2bf(O1[r]);
        }
    }
    if (lane < 16 && prow0 + lane < PP)
        Lsum[((size_t)seg * H + head) * PP + prow0 + lane] = lsum;
}

// --- oproj with split-K combine pre-pass: t2 = comb(Opb,Lsum) @ Wo^T + bo ----
// grid (32, 2), 256 thr. Full-K A tile in LDS (K=E=256).
__global__ __launch_bounds__(256)
void k_ocomb(const unsigned short* __restrict__ Opb,
             const float* __restrict__ Lsum,
             const unsigned short* __restrict__ Bt,
             const float* __restrict__ bias,
             float* __restrict__ C, int M) {
    __shared__ short AsF[64 * 256];   // 32 KB, fragment order over full K
    __shared__ short Bs[128 * 64];    // 16 KB
    __shared__ float invL[64 * 8];
    int tid = threadIdx.x;
    int wave = tid >> 6, lane = tid & 63;
    int quad = lane >> 4, c = lane & 15;
    int m0 = blockIdx.x * 64, n0 = blockIdx.y * 128;
    const unsigned short* Bblk = Bt + (size_t)n0 * E;
    const float* biasblk = bias + n0;

    // pre-pass 1: inverse denominators per (row, head) — 512 entries, 256 thr
    #pragma unroll
    for (int i = tid; i < 512; i += 256) {
        int row = i >> 3, hh = i & 7;
        int rg = m0 + row; if (rg > M - 1) rg = M - 1;
        float L = 0.f;
        #pragma unroll
        for (int s = 0; s < SPLIT; ++s)
            L += Lsum[((size_t)s * H + hh) * PP + rg];
        invL[i] = 1.f / L;
    }
    __syncthreads();
    // pre-pass 2: combine partials -> full-K fragment-ordered A tile
    #pragma unroll
    for (int j = 0; j < 8; ++j) {
        int g = tid + 256 * j;
        int T = g >> 6;
        int row = (T & 3) * 16 + (g & 15);
        int k = (T >> 2) * 32 + ((g >> 4) & 3) * 8;
        int rg = m0 + row; if (rg > M - 1) rg = M - 1;
        float s8[8] = {0,0,0,0,0,0,0,0};
        #pragma unroll
        for (int s = 0; s < SPLIT; ++s) {
            short8 v = *(const short8*)(Opb + ((size_t)s * PP + rg) * E + k);
            #pragma unroll
            for (int e = 0; e < 8; ++e)
                s8[e] += bf2f((unsigned short)v[e]);
        }
        float li = invL[row * 8 + (k >> 5)];
        short8 r8;
        #pragma unroll
        for (int e = 0; e < 8; ++e) r8[e] = (short)f2bf(s8[e] * li);
        *(short8*)(AsF + (size_t)g * 8) = r8;
    }
    // B decode + prefetch
    int bgk[4];
    const unsigned short* brow[4];
    #pragma unroll
    for (int j = 0; j < 4; ++j) {
        int g = tid + 256 * j;
        int T = g >> 6;
        int gn = (T & 7) * 16 + (g & 15);
        bgk[j] = (T >> 3) * 32 + ((g >> 4) & 3) * 8;
        brow[j] = Bblk + (size_t)gn * E;
    }
    short8 pb[4];
    #pragma unroll
    for (int j = 0; j < 4; ++j) pb[j] = *(const short8*)(brow[j] + bgk[j]);

    f32x4 acc[2][4];
    #pragma unroll
    for (int i = 0; i < 2; ++i)
        #pragma unroll
        for (int j = 0; j < 4; ++j)
            acc[i][j] = (f32x4){0.f, 0.f, 0.f, 0.f};
    int wm = wave >> 1, wn = wave & 1;
    for (int kt = 0; kt < 4; ++kt) {
        __syncthreads();   // kt=0: AsF ready; kt>0: prev Bs consumed
        #pragma unroll
        for (int j = 0; j < 4; ++j)
            *(short8*)(Bs + (tid + 256 * j) * 8) = pb[j];
        __syncthreads();
        if (kt + 1 < 4) {
            int k0 = (kt + 1) * 64;
            #pragma unroll
            for (int j = 0; j < 4; ++j) pb[j] = *(const short8*)(brow[j] + k0 + bgk[j]);
        }
        #pragma unroll
        for (int kc = 0; kc < 2; ++kc) {
            short8 af[2], bf[4];
            #pragma unroll
            for (int i = 0; i < 2; ++i)
                af[i] = *(short8*)(AsF + ((kt * 8 + kc * 4 + wm * 2 + i) * 64 + lane) * 8);
            #pragma unroll
            for (int j = 0; j < 4; ++j)
                bf[j] = *(short8*)(Bs + ((kc * 8 + wn * 4 + j) * 64 + lane) * 8);
            #pragma unroll
            for (int i = 0; i < 2; ++i)
                #pragma unroll
                for (int j = 0; j < 4; ++j)
                    acc[i][j] = __builtin_amdgcn_mfma_f32_16x16x32_bf16(
                        af[i], bf[j], acc[i][j], 0, 0, 0);
        }
    }
    #pragma unroll
    for (int j = 0; j < 4; ++j) {
        float bv = biasblk[(wn * 4 + j) * 16 + c];
        int ng = n0 + (wn * 4 + j) * 16 + c;
        #pragma unroll
        for (int i = 0; i < 2; ++i) {
            #pragma unroll
            for (int r = 0; r < 4; ++r) {
                int mg = m0 + (wm * 2 + i) * 16 + quad * 4 + r;
                if (mg < M)
                    C[(size_t)mg * E + ng] = acc[i][j][r] + bv;
            }
        }
    }
}

// --- ff1 with LN1 pre-pass: ffb = relu(LN(q + t2) @ ff1^T + bff1) -----------
// grid (32, 8), 256 thr. by==0 blocks also write LN result fp32 to qB.
__global__ __launch_bounds__(256)
void k_ffln(const float* __restrict__ q, const float* __restrict__ t2,
            const float* __restrict__ lng, const float* __restrict__ lnb,
            float* __restrict__ qB,
            const unsigned short* __restrict__ Bt,
            const float* __restrict__ bias,
            unsigned short* __restrict__ Cb, int M) {
    __shared__ short AsF[64 * 256];   // 32 KB
    __shared__ short Bs[128 * 64];    // 16 KB
    __shared__ float sS[64 * 4], sS2[64 * 4];
    __shared__ float mS[64], rS[64];
    __shared__ float gS[256], bS[256];
    int tid = threadIdx.x;
    int wave = tid >> 6, lane = tid & 63;
    int quad = lane >> 4, c = lane & 15;
    int m0 = blockIdx.x * 64, n0 = blockIdx.y * 128;
    const unsigned short* Bblk = Bt + (size_t)n0 * E;
    const float* biasblk = bias + n0;

    gS[tid] = lng[tid];
    bS[tid] = lnb[tid];
    // pre-pass 1: row stats (4 threads per row)
    {
        int row = tid >> 2, qtr = tid & 3;
        int rg = m0 + row; if (rg > M - 1) rg = M - 1;
        const float* xq = q + (size_t)rg * E + qtr * 64;
        const float* xt = t2 + (size_t)rg * E + qtr * 64;
        float s = 0.f, s2 = 0.f;
        #pragma unroll
        for (int i = 0; i < 16; ++i) {
            float4 a = *(const float4*)(xq + i * 4);
            float4 b = *(const float4*)(xt + i * 4);
            float x0 = a.x + b.x, x1 = a.y + b.y, x2 = a.z + b.z, x3 = a.w + b.w;
            s  += (x0 + x1) + (x2 + x3);
            s2 += (x0*x0 + x1*x1) + (x2*x2 + x3*x3);
        }
        sS[tid] = s; sS2[tid] = s2;
    }
    __syncthreads();
    if (tid < 64) {
        float ts  = sS[tid*4] + sS[tid*4+1] + sS[tid*4+2] + sS[tid*4+3];
        float ts2 = sS2[tid*4] + sS2[tid*4+1] + sS2[tid*4+2] + sS2[tid*4+3];
        float mean = ts * (1.0f / E);
        float var  = ts2 * (1.0f / E) - mean * mean;
        mS[tid] = mean;
        rS[tid] = rsqrtf(var + 1e-5f);
    }
    __syncthreads();
    // pre-pass 2: LN -> full-K A tile (+ fp32 out for by==0)
    bool wr = (blockIdx.y == 0);
    #pragma unroll
    for (int j = 0; j < 8; ++j) {
        int g = tid + 256 * j;
        int T = g >> 6;
        int row = (T & 3) * 16 + (g & 15);
        int k = (T >> 2) * 32 + ((g >> 4) & 3) * 8;
        int rg = m0 + row; if (rg > M - 1) rg = M - 1;
        const float* xq = q + (size_t)rg * E + k;
        const float* xt = t2 + (size_t)rg * E + k;
        float4 a0 = *(const float4*)(xq);
        float4 a1 = *(const float4*)(xq + 4);
        float4 b0 = *(const float4*)(xt);
        float4 b1 = *(const float4*)(xt + 4);
        float mean = mS[row], rstd = rS[row];
        float x[8] = {a0.x+b0.x, a0.y+b0.y, a0.z+b0.z, a0.w+b0.w,
                      a1.x+b1.x, a1.y+b1.y, a1.z+b1.z, a1.w+b1.w};
        float y[8];
        #pragma unroll
        for (int e = 0; e < 8; ++e)
            y[e] = (x[e] - mean) * rstd * gS[k + e] + bS[k + e];
        if (wr && (m0 + row) < M) {
            float4 o0 = {y[0], y[1], y[2], y[3]};
            float4 o1 = {y[4], y[5], y[6], y[7]};
            *(float4*)(qB + (size_t)(m0 + row) * E + k)     = o0;
            *(float4*)(qB + (size_t)(m0 + row) * E + k + 4) = o1;
        }
        short8 r8;
        #pragma unroll
        for (int e = 0; e < 8; ++e) r8[e] = (short)f2bf(y[e]);
        *(short8*)(AsF + (size_t)g * 8) = r8;
    }
    // B decode + prefetch
    int bgk[4];
    const unsigned short* brow[4];
    #pragma unroll
    for (int j = 0; j < 4; ++j) {
        int g = tid + 256 * j;
        int T = g >> 6;
        int gn = (T & 7) * 16 + (g & 15);
        bgk[j] = (T >> 3) * 32 + ((g >> 4) & 3) * 8;
        brow[j] = Bblk + (size_t)gn * E;
    }
    short8 pb[4];
    #pragma unroll
    for (int j = 0; j < 4; ++j) pb[j] = *(const short8*)(brow[j] + bgk[j]);

    f32x4 acc[2][4];
    #pragma unroll
    for (int i = 0; i < 2; ++i)
        #pragma unroll
        for (int j = 0; j < 4; ++j)
            acc[i][j] = (f32x4){0.f, 0.f, 0.f, 0.f};
    int wm = wave >> 1, wn = wave & 1;
    for (int kt = 0; kt < 4; ++kt) {
        __syncthreads();
        #pragma unroll
        for (int j = 0; j < 4; ++j)
            *(short8*)(Bs + (tid + 256 * j) * 8) = pb[j];
        __syncthreads();
        if (kt + 1 < 4) {
            int k0 = (kt + 1) * 64;
            #pragma unroll
            for (int j = 0; j < 4; ++j) pb[j] = *(const short8*)(brow[j] + k0 + bgk[j]);
        }
        #pragma unroll
        for (int kc = 0; kc < 2; ++kc) {
            short8 af[2], bf[4];
            #pragma unroll
            for (int i = 0; i < 2; ++i)
                af[i] = *(short8*)(AsF + ((kt * 8 + kc * 4 + wm * 2 + i) * 64 + lane) * 8);
            #pragma unroll
            for (int j = 0; j < 4; ++j)
                bf[j] = *(short8*)(Bs + ((kc * 8 + wn * 4 + j) * 64 + lane) * 8);
            #pragma unroll
            for (int i = 0; i < 2; ++i)
                #pragma unroll
                for (int j = 0; j < 4; ++j)
                    acc[i][j] = __builtin_amdgcn_mfma_f32_16x16x32_bf16(
                        af[i], bf[j], acc[i][j], 0, 0, 0);
        }
    }
    #pragma unroll
    for (int j = 0; j < 4; ++j) {
        float bv = biasblk[(wn * 4 + j) * 16 + c];
        int ng = n0 + (wn * 4 + j) * 16 + c;
        #pragma unroll
        for (int i = 0; i < 2; ++i) {
            #pragma unroll
            for (int r = 0; r < 4; ++r) {
                int mg = m0 + (wm * 2 + i) * 16 + quad * 4 + r;
                if (mg < M) {
                    float v = fmaxf(acc[i][j][r] + bv, 0.f);
                    Cb[(size_t)mg * FF + ng] = f2bf(v);
                }
            }
        }
    }
}

// ---------------- LN with separate src/dst: qo/qbo = LN(a + b) --------------
__global__ __launch_bounds__(256)
void k_addln2(const float* __restrict__ a, const float* __restrict__ b,
              const float* __restrict__ g, const float* __restrict__ bb,
              float* __restrict__ qo, unsigned short* __restrict__ qbo) {
    int p = blockIdx.x, e = threadIdx.x;
    float x = a[p*E + e] + b[p*E + e];
    float s = x, s2 = x * x;
    #pragma unroll
    for (int off = 1; off < 64; off <<= 1) {
        s  += __shfl_xor(s, off, 64);
        s2 += __shfl_xor(s2, off, 64);
    }
    __shared__ float ps[4], ps2[4];
    int w = e >> 6;
    if ((e & 63) == 0) { ps[w] = s; ps2[w] = s2; }
    __syncthreads();
    float ts  = ps[0] + ps[1] + ps[2] + ps[3];
    float ts2 = ps2[0] + ps2[1] + ps2[2] + ps2[3];
    float mean = ts * (1.0f / E);
    float var  = ts2 * (1.0f / E) - mean * mean;
    float rstd = rsqrtf(var + 1e-5f);
    float v = (x - mean) * rstd * g[e] + bb[e];
    qo[p*E + e] = v;
    qbo[p*E + e] = f2bf(v);
}

// ---------------- contrastive scores + symmetric scatter ----------------
__global__ __launch_bounds__(256)
void k_scores(const float* __restrict__ q, const float* __restrict__ text,
              const int* __restrict__ row, const int* __restrict__ col,
              const float* __restrict__ lsc, float* __restrict__ out) {
    int p = blockIdx.x;
    int tid = threadIdx.x;
    int tt = tid >> 3, l8 = tid & 7;
    const float* qr = q + (size_t)p * E + l8 * 32;
    const float* tr = text + (size_t)tt * E + l8 * 32;
    float s = 0.f;
    #pragma unroll
    for (int i = 0; i < 32; ++i) s += qr[i] * tr[i];
    s += __shfl_xor(s, 1, 8);
    s += __shfl_xor(s, 2, 8);
    s += __shfl_xor(s, 4, 8);
    if (l8 == 0) {
        float v = s * __expf(lsc[0]);
        int r = row[p], cc = col[p];
        out[((size_t)(r * NN + cc)) * TT + tt] = v;
        out[((size_t)(cc * NN + r)) * TT + tt] = v;
    }
}

extern "C" void kernel_launch(void* const* d_in, const int* in_sizes, int n_in,
                              void* d_out, int out_size, void* d_ws, size_t ws_size,
                              hipStream_t stream) {
    const float* h      = (const float*)d_in[0];
    const float* memory = (const float*)d_in[1];
    const float* ref    = (const float*)d_in[2];
    const float* mrt    = (const float*)d_in[3];
    const float* W_pair = (const float*)d_in[6];
    const float* b_pair = (const float*)d_in[7];
    const float* W_mem  = (const float*)d_in[8];
    const float* b_mem  = (const float*)d_in[9];
    const float* W_text = (const float*)d_in[10];
    const float* b_text = (const float*)d_in[11];
    const float* W_ref  = (const float*)d_in[12];
    const float* Wq = (const float*)d_in[13];
    const float* bq = (const float*)d_in[14];
    const float* Wk = (const float*)d_in[15];
    const float* bk = (const float*)d_in[16];
    const float* Wv = (const float*)d_in[17];
    const float* bv = (const float*)d_in[18];
    const float* Wo = (const float*)d_in[19];
    const float* bo = (const float*)d_in[20];
    const float* ln1g = (const float*)d_in[21];
    const float* ln1b = (const float*)d_in[22];
    const float* ln2g = (const float*)d_in[23];
    const float* ln2b = (const float*)d_in[24];
    const float* Wff1 = (const float*)d_in[25];
    const float* bff1 = (const float*)d_in[26];
    const float* Wff2 = (const float*)d_in[27];
    const float* bff2 = (const float*)d_in[28];
    const float* lsc  = (const float*)d_in[29];
    float* out = (float*)d_out;

    const float QS = 0.17677669529663687f * 1.4426950408889634f; // scale*log2e

    // ---------- workspace ----------
    int* rowp = (int*)d_ws;                     // 2048
    int* colp = rowp + 2048;                    // 2048
    float* PA  = (float*)(colp + 2048);
    float* PB  = PA + NN * E;
    float* q   = PB + NN * E;                   // P*E fp32 state (LN2 out / q0)
    float* qB  = q + PP * E;                    // P*E fp32 LN1 out
    float* t2  = qB + PP * E;                   // P*E GEMM fp32 out
    float* txt = t2 + PP * E;                   // T*E
    float* Lsum = txt + TT * E;                 // SPLIT*H*P
    unsigned short* us = (unsigned short*)(Lsum + SPLIT * H * PP);
    unsigned short* Opb   = us;  us += (size_t)SPLIT * PP * E;
    unsigned short* qb    = us;  us += PP * E;
    unsigned short* qph   = us;  us += PP * E;
    unsigned short* ffb   = us;  us += (size_t)PP * FF;
    unsigned short* memb  = us;  us += MM * E;
    unsigned short* memb2 = us;  us += MM * E;
    unsigned short* Kbuf  = us;  us += (size_t)LNUM * MM * E;
    unsigned short* Vtbuf = us;  us += (size_t)LNUM * E * MM;
    unsigned short* Wmem_t = us; us += E * E;
    unsigned short* Wq_t  = us;  us += LNUM * E * E;
    unsigned short* Wk_t  = us;  us += LNUM * E * E;
    unsigned short* Wv_t  = us;  us += LNUM * E * E;
    unsigned short* Wo_t  = us;  us += LNUM * E * E;
    unsigned short* ff1_t = us;  us += LNUM * E * FF;
    unsigned short* ff2_t = us;  us += LNUM * FF * E;

    // ---------- prep: everything input-side in ONE parallel launch ----------
    k_prep<<<4244, 256, 0, stream>>>(W_mem, Wq, Wk, Wv, Wo, Wff1, Wff2, memory,
                                     Wmem_t, Wq_t, Wk_t, Wv_t, Wo_t, ff1_t, ff2_t,
                                     memb, rowp, colp, out, QS,
                                     h, ref, W_pair, b_pair, W_ref, PA, PB,
                                     mrt, W_text, b_text, txt);
    k_qbuild<<<PP, 256, 0, stream>>>(rowp, colp, PA, PB, q, qb);
    k_gemm_mfma<<<dim3(MM/128, E/128), 256, 0, stream>>>(
        memb, Wmem_t, b_mem, nullptr, memb2, MM, E, E, 0, 1.0f);
    k_kvproj<<<dim3(MM/128, 2*LNUM*E/128), 256, 0, stream>>>(
        memb2, Wk_t, Wv_t, bk, bv, Kbuf, Vtbuf);

    const int MP64 = (PP + 63) / 64;  // 32 row tiles
    for (int l = 0; l < LNUM; ++l) {
        // qproj: qb -> qph (scaled)  [64 blocks]
        k_gemm64<<<dim3(MP64, E/128), 256, 0, stream>>>(
            qb, Wq_t + (size_t)l*E*E, bq + l*E, nullptr, qph, PP, E, E, 0, QS);
        // attention -> Opb bf16 / Lsum  [1024 blocks]
        k_attn2<<<dim3(32, H, SPLIT), 256, 0, stream>>>(
            qph, Kbuf + (size_t)l*MM*E, Vtbuf + (size_t)l*E*MM, Opb, Lsum);
        // oproj with combine pre-pass -> t2 fp32  [64 blocks]
        k_ocomb<<<dim3(MP64, E/128), 256, 0, stream>>>(
            Opb, Lsum, Wo_t + (size_t)l*E*E, bo + l*E, t2, PP);
        // ff1 with LN1 pre-pass (reads q,t2; writes qB fp32 + ffb)  [256 blocks]
        k_ffln<<<dim3(MP64, FF/128), 256, 0, stream>>>(
            q, t2, ln1g + l*E, ln1b + l*E, qB,
            ff1_t + (size_t)l*E*FF, bff1 + l*FF, ffb, PP);
        // ff2 -> t2  [64 blocks]
        k_gemm64<<<dim3(MP64, E/128), 256, 0, stream>>>(
            ffb, ff2_t + (size_t)l*FF*E, bff2 + l*E, t2, nullptr, PP, E, FF, 0, 1.0f);
        // LN2: q/qb = LN(qB + t2)  [2016 blocks]
        k_addln2<<<PP, 256, 0, stream>>>(qB, t2, ln2g + l*E, ln2b + l*E, q, qb);
    }

    k_scores<<<PP, 256, 0, stream>>>(q, txt, rowp, colp, lsc, out);
}

// Round 12
// 485.740 us; speedup vs baseline: 1.0812x; 1.0812x over previous
//
#include <hip/hip_runtime.h>
#include <hip/hip_bf16.h>
#include <math.h>

#define E   256
#define H   8
#define DH  32
#define LNUM 4
#define FF  1024
#define NN  64
#define MM  4096
#define TT  32
#define PP  2016   // 64*63/2
#define SPLIT 4
#define SEGLEN (MM/SPLIT)   // 1024
#define NT (SEGLEN/64)      // 16 key-tiles per segment

typedef __attribute__((ext_vector_type(8))) short short8;
typedef __attribute__((ext_vector_type(4))) short short4v;
typedef __attribute__((ext_vector_type(4))) float f32x4;

static __device__ __forceinline__ unsigned short f2bf(float x) {
    unsigned u = __float_as_uint(x);
    u = (u + 0x7fffu + ((u >> 16) & 1u)) >> 16;   // RNE
    return (unsigned short)u;
}
static __device__ __forceinline__ float bf2f(unsigned short u) {
    return __uint_as_float((unsigned)u << 16);
}

// ---------------- transpose-cast body (32x32 tile) ----------------
__device__ __forceinline__ void castT_body(float (*t)[33], const float* src,
        unsigned short* dst, int K, int N, int bx, int by, float scale, int tid) {
    int k0 = bx * 32, n0 = by * 32;
    int tx = tid & 31, ty = tid >> 5;
    #pragma unroll
    for (int i = 0; i < 4; ++i)
        t[ty + 8*i][tx] = src[(size_t)(k0 + ty + 8*i) * N + n0 + tx];
    __syncthreads();
    #pragma unroll
    for (int i = 0; i < 4; ++i)
        dst[(size_t)(n0 + ty + 8*i) * K + k0 + tx] = f2bf(t[tx][ty + 8*i] * scale);
}

// --- mega prep: rowcol+zerodiag+memcast+weight transposes+pairpre+textproj ---
__global__ __launch_bounds__(256)
void k_prep(const float* __restrict__ Wmem, const float* __restrict__ Wq,
            const float* __restrict__ Wk, const float* __restrict__ Wv,
            const float* __restrict__ Wo, const float* __restrict__ Wff1,
            const float* __restrict__ Wff2, const float* __restrict__ memory,
            unsigned short* __restrict__ Wmem_t, unsigned short* __restrict__ Wq_t,
            unsigned short* __restrict__ Wk_t, unsigned short* __restrict__ Wv_t,
            unsigned short* __restrict__ Wo_t, unsigned short* __restrict__ ff1_t,
            unsigned short* __restrict__ ff2_t, unsigned short* __restrict__ memb,
            int* __restrict__ rowp, int* __restrict__ colp,
            float* __restrict__ out, float QS,
            const float* __restrict__ h, const float* __restrict__ ref,
            const float* __restrict__ Wp, const float* __restrict__ bp,
            const float* __restrict__ Wr, float* __restrict__ PA,
            float* __restrict__ PB,
            const float* __restrict__ mrt, const float* __restrict__ Wt,
            const float* __restrict__ bt, float* __restrict__ txt) {
    __shared__ float t[32][33];
    __shared__ float fAs[16 * 68];
    __shared__ float fBs[16 * 68];
    int bid = blockIdx.x;
    int tid = threadIdx.x;
    if (bid < 8) {                     // rowcol
        int p = bid * 256 + tid;
        if (p < PP) {
            int off = p, r = 0;
            while (off >= (NN - 1 - r)) { off -= (NN - 1 - r); r++; }
            rowp[p] = r; colp[p] = r + 1 + off;
        }
        return;
    }
    bid -= 8;
    if (bid < 8) {                     // zerodiag
        int i = bid * 256 + tid;
        if (i < NN * TT) out[(size_t)((i >> 5) * 65) * TT + (i & 31)] = 0.f;
        return;
    }
    bid -= 8;
    if (bid < 1024) {                  // memory -> bf16
        int i = (bid * 256 + tid) * 4;
        float4 v = *(const float4*)(memory + i);
        short4v s;
        s[0] = (short)f2bf(v.x); s[1] = (short)f2bf(v.y);
        s[2] = (short)f2bf(v.z); s[3] = (short)f2bf(v.w);
        *(short4v*)(memb + i) = s;
        return;
    }
    bid -= 1024;
    if (bid < 17 * 64) {               // E x E transposes
        int z = bid >> 6, sub = bid & 63;
        const float* src; unsigned short* dst; float sc = 1.0f;
        if (z == 0)      { src = Wmem;               dst = Wmem_t; }
        else if (z < 5)  { src = Wq + (z-1)*E*E;     dst = Wq_t + (z-1)*E*E; sc = QS; }
        else if (z < 9)  { src = Wk + (z-5)*E*E;     dst = Wk_t + (z-5)*E*E; }
        else if (z < 13) { src = Wv + (z-9)*E*E;     dst = Wv_t + (z-9)*E*E; }
        else             { src = Wo + (z-13)*E*E;    dst = Wo_t + (z-13)*E*E; }
        castT_body(t, src, dst, E, E, sub >> 3, sub & 7, sc, tid);
        return;
    }
    bid -= 17 * 64;
    if (bid < 4 * 256) {               // ff1: K=E, N=FF
        int z = bid >> 8, sub = bid & 255;
        castT_body(t, Wff1 + (size_t)z*E*FF, ff1_t + (size_t)z*E*FF,
                   E, FF, sub >> 5, sub & 31, 1.f, tid);
        return;
    }
    bid -= 1024;
    if (bid < 4 * 256) {               // ff2: K=FF, N=E
        int z = bid >> 8, sub = bid & 255;
        castT_body(t, Wff2 + (size_t)z*FF*E, ff2_t + (size_t)z*FF*E,
                   FF, E, sub >> 3, sub & 7, 1.f, tid);
        return;
    }
    bid -= 1024;
    if (bid < 64) {                    // pairpre
        int r = bid, e = tid;
        float base = 0.5f * bp[e] + 0.5f * (ref[r*4+0] * Wr[e] + ref[r*4+1] * Wr[E + e]);
        float a = base, b = base;
        for (int k = 0; k < E; ++k) {
            float hv = h[r*E + k];
            a += hv * Wp[k*E + e];
            b += hv * Wp[(E + k)*E + e];
        }
        PA[r*E + e] = a;
        PB[r*E + e] = b;
        return;
    }
    // text projection: txt[TT,E] = mrt @ Wt + bt  (4 blocks, 64-col tiles)
    int n0 = (bid - 64) * 64;
    int tx = tid & 15, ty = tid >> 4;
    int am = tid >> 2, ak = (tid & 3) * 4;
    int bk = tid >> 4, bn = (tid & 15) * 4;
    bool avalid = am < TT;
    const float* Arow = mrt + (size_t)(avalid ? am : 0) * E;
    float acc[4][4] = {};
    for (int k0 = 0; k0 < E; k0 += 16) {
        __syncthreads();
        float4 av = make_float4(0.f, 0.f, 0.f, 0.f);
        if (avalid) av = *(const float4*)(Arow + k0 + ak);
        fAs[(ak+0)*68 + am] = av.x;
        fAs[(ak+1)*68 + am] = av.y;
        fAs[(ak+2)*68 + am] = av.z;
        fAs[(ak+3)*68 + am] = av.w;
        *(float4*)&fBs[bk*68 + bn] = *(const float4*)(Wt + (size_t)(k0 + bk) * E + n0 + bn);
        __syncthreads();
        #pragma unroll
        for (int kk = 0; kk < 16; ++kk) {
            float4 a4 = *(float4*)&fAs[kk*68 + ty*4];
            float4 b4 = *(float4*)&fBs[kk*68 + tx*4];
            float aa[4] = {a4.x, a4.y, a4.z, a4.w};
            float bb[4] = {b4.x, b4.y, b4.z, b4.w};
            #pragma unroll
            for (int i = 0; i < 4; ++i)
                #pragma unroll
                for (int j = 0; j < 4; ++j)
                    acc[i][j] += aa[i] * bb[j];
        }
    }
    float4 bi = *(const float4*)(bt + n0 + tx*4);
    float bb[4] = {bi.x, bi.y, bi.z, bi.w};
    #pragma unroll
    for (int i = 0; i < 4; ++i) {
        int m = ty*4 + i;
        if (m < TT) {
            float4 o;
            o.x = acc[i][0] + bb[0]; o.y = acc[i][1] + bb[1];
            o.z = acc[i][2] + bb[2]; o.w = acc[i][3] + bb[3];
            *(float4*)(txt + (size_t)m * E + n0 + tx*4) = o;
        }
    }
}

// ---------------- pair-build: q fp32 + qb bf16 (2016 blocks) ----------------
__global__ __launch_bounds__(256)
void k_qbuild(const int* __restrict__ row, const int* __restrict__ col,
              const float* __restrict__ PA, const float* __restrict__ PB,
              float* __restrict__ q, unsigned short* __restrict__ qb) {
    int p = blockIdx.x, e = threadIdx.x;
    float v = PA[row[p]*E + e] + PB[col[p]*E + e];
    q[p*E + e] = v;
    qb[p*E + e] = f2bf(v);
}

// ------------- 128x128-tile bf16 MFMA GEMM (for M=4096 GEMMs) --------------
__global__ __launch_bounds__(256)
void k_gemm_mfma(const unsigned short* __restrict__ A,
                 const unsigned short* __restrict__ Bt,
                 const float* __restrict__ bias,
                 float* __restrict__ C, unsigned short* __restrict__ Cb,
                 int M, int N, int K, int relu, float bscale) {
    __shared__ short As[128 * 64];
    __shared__ short Bs[128 * 64];
    int tid = threadIdx.x;
    int wave = tid >> 6, lane = tid & 63;
    int quad = lane >> 4, c = lane & 15;
    int m0 = blockIdx.x * 128, n0 = blockIdx.y * 128;
    const unsigned short* Bblk = Bt + (size_t)n0 * K;
    const float* biasblk = bias + n0;

    int gm[4], gk[4];
    const unsigned short* arow[4];
    #pragma unroll
    for (int j = 0; j < 4; ++j) {
        int g = tid + 256 * j;
        int T = g >> 6;
        gm[j] = (T & 7) * 16 + (g & 15);
        gk[j] = (T >> 3) * 32 + ((g >> 4) & 3) * 8;
        int r = m0 + gm[j];
        arow[j] = A + (size_t)(r < M ? r : M - 1) * K;
    }
    short8 pa[4], pb[4];
    #pragma unroll
    for (int j = 0; j < 4; ++j) {
        pa[j] = *(const short8*)(arow[j] + gk[j]);
        pb[j] = *(const short8*)(Bblk + (size_t)gm[j] * K + gk[j]);
    }
    f32x4 acc[4][4];
    #pragma unroll
    for (int i = 0; i < 4; ++i)
        #pragma unroll
        for (int j = 0; j < 4; ++j)
            acc[i][j] = (f32x4){0.f, 0.f, 0.f, 0.f};

    int wmt = (wave >> 1) * 4;
    int wnt = (wave & 1) * 4;
    int nk = K >> 6;
    for (int kt = 0; kt < nk; ++kt) {
        __syncthreads();
        #pragma unroll
        for (int j = 0; j < 4; ++j) {
            *(short8*)(As + (tid + 256 * j) * 8) = pa[j];
            *(short8*)(Bs + (tid + 256 * j) * 8) = pb[j];
        }
        __syncthreads();
        if (kt + 1 < nk) {
            int k0 = (kt + 1) * 64;
            #pragma unroll
            for (int j = 0; j < 4; ++j) {
                pa[j] = *(const short8*)(arow[j] + k0 + gk[j]);
                pb[j] = *(const short8*)(Bblk + (size_t)gm[j] * K + k0 + gk[j]);
            }
        }
        #pragma unroll
        for (int kc = 0; kc < 2; ++kc) {
            short8 af[4], bf[4];
            #pragma unroll
            for (int i = 0; i < 4; ++i)
                af[i] = *(short8*)(As + ((kc * 8 + wmt + i) * 64 + lane) * 8);
            #pragma unroll
            for (int j = 0; j < 4; ++j)
                bf[j] = *(short8*)(Bs + ((kc * 8 + wnt + j) * 64 + lane) * 8);
            #pragma unroll
            for (int i = 0; i < 4; ++i)
                #pragma unroll
                for (int j = 0; j < 4; ++j)
                    acc[i][j] = __builtin_amdgcn_mfma_f32_16x16x32_bf16(
                        af[i], bf[j], acc[i][j], 0, 0, 0);
        }
    }
    #pragma unroll
    for (int j = 0; j < 4; ++j) {
        float bv = biasblk[(wnt + j) * 16 + c] * bscale;
        int ng = n0 + (wnt + j) * 16 + c;
        #pragma unroll
        for (int i = 0; i < 4; ++i) {
            #pragma unroll
            for (int r = 0; r < 4; ++r) {
                int mg = m0 + (wmt + i) * 16 + quad * 4 + r;
                if (mg < M) {
                    float v = acc[i][j][r] + bv;
                    if (relu) v = fmaxf(v, 0.f);
                    size_t idx = (size_t)mg * N + ng;
                    if (C) C[idx] = v;
                    if (Cb) Cb[idx] = f2bf(v);
                }
            }
        }
    }
}

// --------- 64x128-tile bf16 MFMA GEMM (R9-proven) --------
__global__ __launch_bounds__(256)
void k_gemm64(const unsigned short* __restrict__ A,
              const unsigned short* __restrict__ Bt,
              const float* __restrict__ bias,
              float* __restrict__ C, unsigned short* __restrict__ Cb,
              int M, int N, int K, int relu, float bscale) {
    __shared__ short As[64 * 64];
    __shared__ short Bs[128 * 64];
    int tid = threadIdx.x;
    int wave = tid >> 6, lane = tid & 63;
    int quad = lane >> 4, c = lane & 15;
    int m0 = blockIdx.x * 64, n0 = blockIdx.y * 128;
    const unsigned short* Bblk = Bt + (size_t)n0 * K;
    const float* biasblk = bias + n0;

    int agk[2];
    const unsigned short* arow[2];
    #pragma unroll
    for (int j = 0; j < 2; ++j) {
        int g = tid + 256 * j;
        int T = g >> 6;
        int gm = (T & 3) * 16 + (g & 15);
        agk[j] = (T >> 2) * 32 + ((g >> 4) & 3) * 8;
        int r = m0 + gm;
        arow[j] = A + (size_t)(r < M ? r : M - 1) * K;
    }
    int bgk[4];
    const unsigned short* brow[4];
    #pragma unroll
    for (int j = 0; j < 4; ++j) {
        int g = tid + 256 * j;
        int T = g >> 6;
        int gn = (T & 7) * 16 + (g & 15);
        bgk[j] = (T >> 3) * 32 + ((g >> 4) & 3) * 8;
        brow[j] = Bblk + (size_t)gn * K;
    }
    short8 pa[2], pb[4];
    #pragma unroll
    for (int j = 0; j < 2; ++j) pa[j] = *(const short8*)(arow[j] + agk[j]);
    #pragma unroll
    for (int j = 0; j < 4; ++j) pb[j] = *(const short8*)(brow[j] + bgk[j]);

    f32x4 acc[2][4];
    #pragma unroll
    for (int i = 0; i < 2; ++i)
        #pragma unroll
        for (int j = 0; j < 4; ++j)
            acc[i][j] = (f32x4){0.f, 0.f, 0.f, 0.f};

    int wm = wave >> 1;
    int wn = wave & 1;
    int nk = K >> 6;
    for (int kt = 0; kt < nk; ++kt) {
        __syncthreads();
        #pragma unroll
        for (int j = 0; j < 2; ++j)
            *(short8*)(As + (tid + 256 * j) * 8) = pa[j];
        #pragma unroll
        for (int j = 0; j < 4; ++j)
            *(short8*)(Bs + (tid + 256 * j) * 8) = pb[j];
        __syncthreads();
        if (kt + 1 < nk) {
            int k0 = (kt + 1) * 64;
            #pragma unroll
            for (int j = 0; j < 2; ++j) pa[j] = *(const short8*)(arow[j] + k0 + agk[j]);
            #pragma unroll
            for (int j = 0; j < 4; ++j) pb[j] = *(const short8*)(brow[j] + k0 + bgk[j]);
        }
        #pragma unroll
        for (int kc = 0; kc < 2; ++kc) {
            short8 af[2], bf[4];
            #pragma unroll
            for (int i = 0; i < 2; ++i)
                af[i] = *(short8*)(As + ((kc * 4 + wm * 2 + i) * 64 + lane) * 8);
            #pragma unroll
            for (int j = 0; j < 4; ++j)
                bf[j] = *(short8*)(Bs + ((kc * 8 + wn * 4 + j) * 64 + lane) * 8);
            #pragma unroll
            for (int i = 0; i < 2; ++i)
                #pragma unroll
                for (int j = 0; j < 4; ++j)
                    acc[i][j] = __builtin_amdgcn_mfma_f32_16x16x32_bf16(
                        af[i], bf[j], acc[i][j], 0, 0, 0);
        }
    }
    #pragma unroll
    for (int j = 0; j < 4; ++j) {
        float bv = biasblk[(wn * 4 + j) * 16 + c] * bscale;
        int ng = n0 + (wn * 4 + j) * 16 + c;
        #pragma unroll
        for (int i = 0; i < 2; ++i) {
            #pragma unroll
            for (int r = 0; r < 4; ++r) {
                int mg = m0 + (wm * 2 + i) * 16 + quad * 4 + r;
                if (mg < M) {
                    float v = acc[i][j][r] + bv;
                    if (relu) v = fmaxf(v, 0.f);
                    size_t idx = (size_t)mg * N + ng;
                    if (C) C[idx] = v;
                    if (Cb) Cb[idx] = f2bf(v);
                }
            }
        }
    }
}

// ------- all-layer K/V projection ------------------------------------------
__global__ __launch_bounds__(256)
void k_kvproj(const unsigned short* __restrict__ A,
              const unsigned short* __restrict__ Wk_t,
              const unsigned short* __restrict__ Wv_t,
              const float* __restrict__ bk, const float* __restrict__ bv,
              unsigned short* __restrict__ Kout,
              unsigned short* __restrict__ Vtout) {
    __shared__ short As[128 * 64];
    __shared__ short Bs[128 * 64];
    int tid = threadIdx.x;
    int wave = tid >> 6, lane = tid & 63;
    int quad = lane >> 4, c = lane & 15;
    int m0 = blockIdx.x * 128, n0 = blockIdx.y * 128;
    int l = n0 >> 9, kv = (n0 >> 8) & 1, c0 = n0 & 255;
    const unsigned short* Bblk = (kv ? Wv_t : Wk_t) + (size_t)(l * E + c0) * E;
    const float* biasblk = (kv ? bv : bk) + l * E + c0;

    int gm[4], gk[4];
    const unsigned short* arow[4];
    #pragma unroll
    for (int j = 0; j < 4; ++j) {
        int g = tid + 256 * j;
        int T = g >> 6;
        gm[j] = (T & 7) * 16 + (g & 15);
        gk[j] = (T >> 3) * 32 + ((g >> 4) & 3) * 8;
        arow[j] = A + (size_t)(m0 + gm[j]) * E;
    }
    short8 pa[4], pb[4];
    #pragma unroll
    for (int j = 0; j < 4; ++j) {
        pa[j] = *(const short8*)(arow[j] + gk[j]);
        pb[j] = *(const short8*)(Bblk + (size_t)gm[j] * E + gk[j]);
    }
    f32x4 acc[4][4];
    #pragma unroll
    for (int i = 0; i < 4; ++i)
        #pragma unroll
        for (int j = 0; j < 4; ++j)
            acc[i][j] = (f32x4){0.f, 0.f, 0.f, 0.f};
    int wmt = (wave >> 1) * 4;
    int wnt = (wave & 1) * 4;
    for (int kt = 0; kt < 4; ++kt) {
        __syncthreads();
        #pragma unroll
        for (int j = 0; j < 4; ++j) {
            *(short8*)(As + (tid + 256 * j) * 8) = pa[j];
            *(short8*)(Bs + (tid + 256 * j) * 8) = pb[j];
        }
        __syncthreads();
        if (kt + 1 < 4) {
            int k0 = (kt + 1) * 64;
            #pragma unroll
            for (int j = 0; j < 4; ++j) {
                pa[j] = *(const short8*)(arow[j] + k0 + gk[j]);
                pb[j] = *(const short8*)(Bblk + (size_t)gm[j] * E + k0 + gk[j]);
            }
        }
        #pragma unroll
        for (int kc = 0; kc < 2; ++kc) {
            short8 af[4], bf[4];
            #pragma unroll
            for (int i = 0; i < 4; ++i)
                af[i] = *(short8*)(As + ((kc * 8 + wmt + i) * 64 + lane) * 8);
            #pragma unroll
            for (int j = 0; j < 4; ++j)
                bf[j] = *(short8*)(Bs + ((kc * 8 + wnt + j) * 64 + lane) * 8);
            #pragma unroll
            for (int i = 0; i < 4; ++i)
                #pragma unroll
                for (int j = 0; j < 4; ++j)
                    acc[i][j] = __builtin_amdgcn_mfma_f32_16x16x32_bf16(
                        af[i], bf[j], acc[i][j], 0, 0, 0);
        }
    }
    if (!kv) {
        unsigned short* Kp = Kout + (size_t)l * MM * E;
        #pragma unroll
        for (int j = 0; j < 4; ++j) {
            float bz = biasblk[(wnt + j) * 16 + c];
            int ng = c0 + (wnt + j) * 16 + c;
            #pragma unroll
            for (int i = 0; i < 4; ++i)
                #pragma unroll
                for (int r = 0; r < 4; ++r) {
                    int mg = m0 + (wmt + i) * 16 + quad * 4 + r;
                    Kp[(size_t)mg * E + ng] = f2bf(acc[i][j][r] + bz);
                }
        }
    } else {
        unsigned short* Vp = Vtout + (size_t)l * E * MM;
        #pragma unroll
        for (int j = 0; j < 4; ++j) {
            float bz = biasblk[(wnt + j) * 16 + c];
            int ng = c0 + (wnt + j) * 16 + c;
            #pragma unroll
            for (int i = 0; i < 4; ++i) {
                int mb = m0 + (wmt + i) * 16 + quad * 4;
                short4v s4;
                #pragma unroll
                for (int r = 0; r < 4; ++r) s4[r] = (short)f2bf(acc[i][j][r] + bz);
                *(short4v*)(Vp + (size_t)ng * MM + mb) = s4;
            }
        }
    }
}

// -------- flash cross-attention (R9 structure, bf16 partials) ---------------
__global__ __launch_bounds__(256)
void k_attn2(const unsigned short* __restrict__ qph,
             const unsigned short* __restrict__ Kb,
             const unsigned short* __restrict__ Vt,
             unsigned short* __restrict__ Opb, float* __restrict__ Lsum) {
    __shared__ short KV[2 * 512 * 8];
    __shared__ short Plds[4 * 16 * 64];
    int tid = threadIdx.x;
    int wave = tid >> 6, lane = tid & 63;
    int quad = lane >> 4, c = lane & 15;
    int head = blockIdx.y, seg = blockIdx.z;
    int hc = head * DH;
    int prow0 = blockIdx.x * 64 + wave * 16;

    int pq = prow0 + c; if (pq > PP - 1) pq = PP - 1;
    short8 qf = *(const short8*)(qph + (size_t)pq * E + hc + quad * 8);

    int l = tid & 63;
    int tK = tid >> 6;
    const unsigned short* kgp = Kb + (size_t)(tK * 16 + (l & 15)) * E + hc + ((l >> 4) & 3) * 8;
    int sV = tid >> 7, ntV = (tid >> 6) & 1;
    const unsigned short* vgp = Vt + (size_t)(hc + ntV * 16 + (l & 15)) * MM
                                + sV * 32 + ((l >> 4) & 3) * 8;

    short* Pw = Plds + wave * 1024 + c * 64;
    int sw = (c & 7) << 1;

    f32x4 O0 = {0,0,0,0}, O1 = {0,0,0,0};
    float lsum = 0.f;

    int m0 = seg * SEGLEN;
    short8 pk = *(const short8*)(kgp + (size_t)m0 * E);
    short8 pv = *(const short8*)(vgp + m0);
    *(short8*)(KV + (size_t)tid * 8) = pk;
    *(short8*)(KV + ((size_t)256 + tid) * 8) = pv;

    int cur = 0;
    for (int kt = 0; kt < NT; ++kt) {
        __syncthreads();
        if (kt + 1 < NT) {
            int m1 = m0 + (kt + 1) * 64;
            pk = *(const short8*)(kgp + (size_t)m1 * E);
            pv = *(const short8*)(vgp + m1);
        }
        const short* Kc = KV + (size_t)cur * 512 * 8;
        f32x4 st[4];
        #pragma unroll
        for (int t = 0; t < 4; ++t) {
            short8 kf = *(const short8*)(Kc + (t * 64 + lane) * 8);
            f32x4 z = {0,0,0,0};
            st[t] = __builtin_amdgcn_mfma_f32_16x16x32_bf16(kf, qf, z, 0, 0, 0);
        }
        #pragma unroll
        for (int t = 0; t < 4; ++t) {
            float p0 = __builtin_amdgcn_exp2f(st[t][0]);
            float p1 = __builtin_amdgcn_exp2f(st[t][1]);
            float p2 = __builtin_amdgcn_exp2f(st[t][2]);
            float p3 = __builtin_amdgcn_exp2f(st[t][3]);
            lsum += (p0 + p1) + (p2 + p3);
            unsigned lo = (__float_as_uint(p1) & 0xffff0000u) | (__float_as_uint(p0) >> 16);
            unsigned hi = (__float_as_uint(p3) & 0xffff0000u) | (__float_as_uint(p2) >> 16);
            uint2 w; w.x = lo; w.y = hi;
            *(uint2*)(Pw + ((((t << 2) + quad) ^ sw) << 2)) = w;
        }
        const short* Vc = Kc + 256 * 8;
        #pragma unroll
        for (int s = 0; s < 2; ++s) {
            short8 pf  = *(const short8*)(Pw + (((s * 8 + 2 * quad) ^ sw) << 2));
            short8 vf0 = *(const short8*)(Vc + ((s * 2 + 0) * 64 + lane) * 8);
            short8 vf1 = *(const short8*)(Vc + ((s * 2 + 1) * 64 + lane) * 8);
            O0 = __builtin_amdgcn_mfma_f32_16x16x32_bf16(pf, vf0, O0, 0, 0, 0);
            O1 = __builtin_amdgcn_mfma_f32_16x16x32_bf16(pf, vf1, O1, 0, 0, 0);
        }
        if (kt + 1 < NT) {
            int nb = cur ^ 1;
            *(short8*)(KV + ((size_t)nb * 512 + tid) * 8) = pk;
            *(short8*)(KV + ((size_t)nb * 512 + 256 + tid) * 8) = pv;
        }
        cur ^= 1;
    }
    lsum += __shfl_xor(lsum, 16, 64);
    lsum += __shfl_xor(lsum, 32, 64);
    #pragma unroll
    for (int r = 0; r < 4; ++r) {
        int pg = prow0 + quad * 4 + r;
        if (pg < PP) {
            Opb[((size_t)seg * PP + pg) * E + hc + c]      = f2bf(O0[r]);
            Opb[((size_t)seg * PP + pg) * E + hc + 16 + c] = f2bf(O1[r]);
        }
    }
    if (lane < 16 && prow0 + lane < PP)
        Lsum[((size_t)seg * H + head) * PP + prow0 + lane] = lsum;
}

// ---------------- merge split-K partials (bf16 in) -> attb bf16 -------------
__global__ __launch_bounds__(256)
void k_comb(const unsigned short* __restrict__ Opb, const float* __restrict__ Lsum,
            unsigned short* __restrict__ attb) {
    int p = blockIdx.x, e = threadIdx.x, h = e >> 5;
    float L = 0.f, o = 0.f;
    #pragma unroll
    for (int s = 0; s < SPLIT; ++s) {
        L += Lsum[((size_t)s * H + h) * PP + p];
        o += bf2f(Opb[((size_t)s * PP + p) * E + e]);
    }
    attb[(size_t)p * E + e] = f2bf(o / L);
}

// ---------------- fused residual add + LayerNorm (R9-proven) ----------------
__global__ __launch_bounds__(256)
void k_addln(float* __restrict__ q, const float* __restrict__ r,
             const float* __restrict__ g, const float* __restrict__ b,
             unsigned short* __restrict__ qb) {
    int p = blockIdx.x, e = threadIdx.x;
    float x = q[p*E + e] + r[p*E + e];
    float s = x, s2 = x * x;
    #pragma unroll
    for (int off = 1; off < 64; off <<= 1) {
        s  += __shfl_xor(s, off, 64);
        s2 += __shfl_xor(s2, off, 64);
    }
    __shared__ float ps[4], ps2[4];
    int w = e >> 6;
    if ((e & 63) == 0) { ps[w] = s; ps2[w] = s2; }
    __syncthreads();
    float ts  = ps[0] + ps[1] + ps[2] + ps[3];
    float ts2 = ps2[0] + ps2[1] + ps2[2] + ps2[3];
    float mean = ts * (1.0f / E);
    float var  = ts2 * (1.0f / E) - mean * mean;
    float rstd = rsqrtf(var + 1e-5f);
    float v = (x - mean) * rstd * g[e] + b[e];
    q[p*E + e] = v;
    qb[p*E + e] = f2bf(v);
}

// ---------------- contrastive scores + symmetric scatter ----------------
__global__ __launch_bounds__(256)
void k_scores(const float* __restrict__ q, const float* __restrict__ text,
              const int* __restrict__ row, const int* __restrict__ col,
              const float* __restrict__ lsc, float* __restrict__ out) {
    int p = blockIdx.x;
    int tid = threadIdx.x;
    int tt = tid >> 3, l8 = tid & 7;
    const float* qr = q + (size_t)p * E + l8 * 32;
    const float* tr = text + (size_t)tt * E + l8 * 32;
    float s = 0.f;
    #pragma unroll
    for (int i = 0; i < 32; ++i) s += qr[i] * tr[i];
    s += __shfl_xor(s, 1, 8);
    s += __shfl_xor(s, 2, 8);
    s += __shfl_xor(s, 4, 8);
    if (l8 == 0) {
        float v = s * __expf(lsc[0]);
        int r = row[p], cc = col[p];
        out[((size_t)(r * NN + cc)) * TT + tt] = v;
        out[((size_t)(cc * NN + r)) * TT + tt] = v;
    }
}

extern "C" void kernel_launch(void* const* d_in, const int* in_sizes, int n_in,
                              void* d_out, int out_size, void* d_ws, size_t ws_size,
                              hipStream_t stream) {
    const float* h      = (const float*)d_in[0];
    const float* memory = (const float*)d_in[1];
    const float* ref    = (const float*)d_in[2];
    const float* mrt    = (const float*)d_in[3];
    const float* W_pair = (const float*)d_in[6];
    const float* b_pair = (const float*)d_in[7];
    const float* W_mem  = (const float*)d_in[8];
    const float* b_mem  = (const float*)d_in[9];
    const float* W_text = (const float*)d_in[10];
    const float* b_text = (const float*)d_in[11];
    const float* W_ref  = (const float*)d_in[12];
    const float* Wq = (const float*)d_in[13];
    const float* bq = (const float*)d_in[14];
    const float* Wk = (const float*)d_in[15];
    const float* bk = (const float*)d_in[16];
    const float* Wv = (const float*)d_in[17];
    const float* bv = (const float*)d_in[18];
    const float* Wo = (const float*)d_in[19];
    const float* bo = (const float*)d_in[20];
    const float* ln1g = (const float*)d_in[21];
    const float* ln1b = (const float*)d_in[22];
    const float* ln2g = (const float*)d_in[23];
    const float* ln2b = (const float*)d_in[24];
    const float* Wff1 = (const float*)d_in[25];
    const float* bff1 = (const float*)d_in[26];
    const float* Wff2 = (const float*)d_in[27];
    const float* bff2 = (const float*)d_in[28];
    const float* lsc  = (const float*)d_in[29];
    float* out = (float*)d_out;

    const float QS = 0.17677669529663687f * 1.4426950408889634f; // scale*log2e

    // ---------- workspace ----------
    int* rowp = (int*)d_ws;                     // 2048
    int* colp = rowp + 2048;                    // 2048
    float* PA  = (float*)(colp + 2048);
    float* PB  = PA + NN * E;
    float* q   = PB + NN * E;                   // P*E fp32 state
    float* t2  = q + PP * E;                    // P*E GEMM fp32 out
    float* txt = t2 + PP * E;                   // T*E
    float* Lsum = txt + TT * E;                 // SPLIT*H*P
    unsigned short* us = (unsigned short*)(Lsum + SPLIT * H * PP);
    unsigned short* Opb   = us;  us += (size_t)SPLIT * PP * E;
    unsigned short* qb    = us;  us += PP * E;
    unsigned short* qph   = us;  us += PP * E;
    unsigned short* attb  = us;  us += PP * E;
    unsigned short* ffb   = us;  us += (size_t)PP * FF;
    unsigned short* memb  = us;  us += MM * E;
    unsigned short* memb2 = us;  us += MM * E;
    unsigned short* Kbuf  = us;  us += (size_t)LNUM * MM * E;
    unsigned short* Vtbuf = us;  us += (size_t)LNUM * E * MM;
    unsigned short* Wmem_t = us; us += E * E;
    unsigned short* Wq_t  = us;  us += LNUM * E * E;
    unsigned short* Wk_t  = us;  us += LNUM * E * E;
    unsigned short* Wv_t  = us;  us += LNUM * E * E;
    unsigned short* Wo_t  = us;  us += LNUM * E * E;
    unsigned short* ff1_t = us;  us += LNUM * E * FF;
    unsigned short* ff2_t = us;  us += LNUM * FF * E;

    // ---------- prep: everything input-side in ONE parallel launch ----------
    k_prep<<<4244, 256, 0, stream>>>(W_mem, Wq, Wk, Wv, Wo, Wff1, Wff2, memory,
                                     Wmem_t, Wq_t, Wk_t, Wv_t, Wo_t, ff1_t, ff2_t,
                                     memb, rowp, colp, out, QS,
                                     h, ref, W_pair, b_pair, W_ref, PA, PB,
                                     mrt, W_text, b_text, txt);
    k_qbuild<<<PP, 256, 0, stream>>>(rowp, colp, PA, PB, q, qb);
    k_gemm_mfma<<<dim3(MM/128, E/128), 256, 0, stream>>>(
        memb, Wmem_t, b_mem, nullptr, memb2, MM, E, E, 0, 1.0f);
    k_kvproj<<<dim3(MM/128, 2*LNUM*E/128), 256, 0, stream>>>(
        memb2, Wk_t, Wv_t, bk, bv, Kbuf, Vtbuf);

    const int MP64 = (PP + 63) / 64;  // 32 row tiles
    for (int l = 0; l < LNUM; ++l) {
        // qproj: qb -> qph (scaled)  [64 blocks]
        k_gemm64<<<dim3(MP64, E/128), 256, 0, stream>>>(
            qb, Wq_t + (size_t)l*E*E, bq + l*E, nullptr, qph, PP, E, E, 0, QS);
        // attention -> Opb bf16 / Lsum  [1024 blocks]
        k_attn2<<<dim3(32, H, SPLIT), 256, 0, stream>>>(
            qph, Kbuf + (size_t)l*MM*E, Vtbuf + (size_t)l*E*MM, Opb, Lsum);
        // combine -> attb bf16  [2016 blocks]
        k_comb<<<PP, 256, 0, stream>>>(Opb, Lsum, attb);
        // oproj -> t2 fp32  [64 blocks]
        k_gemm64<<<dim3(MP64, E/128), 256, 0, stream>>>(
            attb, Wo_t + (size_t)l*E*E, bo + l*E, t2, nullptr, PP, E, E, 0, 1.0f);
        // LN1: q = LN(q + t2)  [2016 blocks]
        k_addln<<<PP, 256, 0, stream>>>(q, t2, ln1g + l*E, ln1b + l*E, qb);
        // ff1 (relu): qb -> ffb  [256 blocks]
        k_gemm64<<<dim3(MP64, FF/128), 256, 0, stream>>>(
            qb, ff1_t + (size_t)l*E*FF, bff1 + l*FF, nullptr, ffb, PP, FF, E, 1, 1.0f);
        // ff2 -> t2  [64 blocks]
        k_gemm64<<<dim3(MP64, E/128), 256, 0, stream>>>(
            ffb, ff2_t + (size_t)l*FF*E, bff2 + l*E, t2, nullptr, PP, E, FF, 0, 1.0f);
        // LN2: q = LN(q + t2)  [2016 blocks]
        k_addln<<<PP, 256, 0, stream>>>(q, t2, ln2g + l*E, ln2b + l*E, qb);
    }

    k_scores<<<PP, 256, 0, stream>>>(q, txt, rowp, colp, lsc, out);
}